// Round 4
// baseline (1983.784 us; speedup 1.0000x reference)
//
#include <hip/hip_runtime.h>
#include <math.h>

#define T_ 12
#define N_ 2048
#define D_ 128
#define ND_ 262144            // N_*D_ = 2^18
#define TND_ 3145728L         // T_*ND_

typedef __attribute__((ext_vector_type(8))) short short8;   // 8 bf16 (4 VGPRs)
typedef __attribute__((ext_vector_type(4))) float f32x4;
typedef __attribute__((ext_vector_type(4))) unsigned int u32x4;
typedef union { float4 v; float a[4]; } f4u;
typedef union { short8 s8; u32x4 u; } frag_u;

__device__ __forceinline__ ushort f2b(float f) {            // fp32 -> bf16 RNE
  unsigned u = __float_as_uint(f);
  u += 0x7fffu + ((u >> 16) & 1u);
  return (ushort)(u >> 16);
}
__device__ __forceinline__ float b2f(ushort s) {
  return __uint_as_float(((unsigned)s) << 16);
}

// Direct global->LDS DMA, 16B per lane. LDS dest is wave-uniform base;
// HW writes lane l's 16B at base + l*16 (m97/m104).
__device__ __forceinline__ void gload16(const ushort* g, ushort* lds) {
  __builtin_amdgcn_global_load_lds(
      (const __attribute__((address_space(1))) void*)g,
      (__attribute__((address_space(3))) void*)lds, 16, 0, 0);
}

// cos/sin(2*pi*k/12); cos(2*pi*f*t/12) == COS12[(f*t)%12]
__constant__ float COS12[12] = {
    1.0f, 0.8660254037844387f, 0.5f, 0.0f, -0.5f, -0.8660254037844387f,
    -1.0f, -0.8660254037844387f, -0.5f, 0.0f, 0.5f, 0.8660254037844387f};
__constant__ float SIN12[12] = {
    0.0f, 0.5f, 0.8660254037844387f, 1.0f, 0.8660254037844387f, 0.5f,
    0.0f, -0.5f, -0.8660254037844387f, -1.0f, -0.8660254037844387f, -0.5f};

// ---------------------------------------------------------------------------
// bf16 MFMA GEMM: C[M,N] = ACT( alpha * A@B^T + bias ), tile 128x128, BK=32.
// (unchanged from round 3 — see comments there)
// ---------------------------------------------------------------------------
template <int ACT, int OUT>
__global__ __launch_bounds__(256) void mgemm(
    const ushort* __restrict__ A, const ushort* __restrict__ B,
    const float* __restrict__ bias, void* __restrict__ Cv,
    int K, int lda, int ldb, int ldc, float alpha,
    long sAb, long sBb, long sCb, int off0, int off1) {
  __shared__ ushort As[4096];
  __shared__ ushort Bs[4096];
  const int tid = threadIdx.x;
  const int w = tid >> 6;
  const int l = tid & 63;
  const int lr = l & 15;        // fragment row/col within 16
  const int lg = l >> 4;        // k-group (0..3)
  const int row0 = blockIdx.y * 128;
  const int col0 = blockIdx.x * 128;
  const ushort* Ap = A + sAb * blockIdx.z;
  const ushort* Bp = B + sBb * blockIdx.z;

  f32x4 acc[2][8];
#pragma unroll
  for (int i = 0; i < 2; ++i)
#pragma unroll
    for (int j = 0; j < 8; ++j) acc[i][j] = (f32x4){0.f, 0.f, 0.f, 0.f};

  const int ba = w, bb2 = w + 4;
  const ushort* Apl = Ap + (long)(row0 + ba * 16 + lr) * lda + lg * 8;
  const ushort* Apl2 = Ap + (long)(row0 + bb2 * 16 + lr) * lda + lg * 8;
  const ushort* Bpl = Bp + (long)(col0 + ba * 16 + lr) * ldb + lg * 8;
  const ushort* Bpl2 = Bp + (long)(col0 + bb2 * 16 + lr) * ldb + lg * 8;
  for (int k0 = 0; k0 < K; k0 += 32) {
    gload16(Apl + k0, As + ba * 512);
    gload16(Apl2 + k0, As + bb2 * 512);
    gload16(Bpl + k0, Bs + ba * 512);
    gload16(Bpl2 + k0, Bs + bb2 * 512);
    __syncthreads();
    const short8 a0 = *(const short8*)(As + (w * 2 + 0) * 512 + l * 8);
    const short8 a1 = *(const short8*)(As + (w * 2 + 1) * 512 + l * 8);
#pragma unroll
    for (int ni = 0; ni < 8; ++ni) {
      const short8 bfr = *(const short8*)(Bs + ni * 512 + l * 8);
      acc[0][ni] = __builtin_amdgcn_mfma_f32_16x16x32_bf16(a0, bfr, acc[0][ni], 0, 0, 0);
      acc[1][ni] = __builtin_amdgcn_mfma_f32_16x16x32_bf16(a1, bfr, acc[1][ni], 0, 0, 0);
    }
    __syncthreads();
  }

  const long Cz = sCb * blockIdx.z;
#pragma unroll
  for (int mi = 0; mi < 2; ++mi) {
    const int grow0 = row0 + w * 32 + mi * 16 + lg * 4;
    if (OUT == 2) {
      ushort* C = (ushort*)Cv;
#pragma unroll
      for (int ni = 0; ni < 8; ++ni) {
        const int c = col0 + ni * 16 + lr;
        const float bv = bias ? bias[c] : 0.f;
        ushort4 pk;
        float v0 = acc[mi][ni][0] * alpha + bv;
        float v1 = acc[mi][ni][1] * alpha + bv;
        float v2 = acc[mi][ni][2] * alpha + bv;
        float v3 = acc[mi][ni][3] * alpha + bv;
        if (ACT == 1) { v0 = fmaxf(v0, 0.f); v1 = fmaxf(v1, 0.f); v2 = fmaxf(v2, 0.f); v3 = fmaxf(v3, 0.f); }
        pk.x = f2b(v0); pk.y = f2b(v1); pk.z = f2b(v2); pk.w = f2b(v3);
        *(ushort4*)(C + (long)c * ldc + grow0) = pk;
      }
    } else {
#pragma unroll
      for (int ni = 0; ni < 8; ++ni) {
        const int c = col0 + ni * 16 + lr;
        const float bv = bias ? bias[c] : 0.f;
        const int cm = c + (c < 128 ? off0 : off1);
#pragma unroll
        for (int r = 0; r < 4; ++r) {
          float v = acc[mi][ni][r] * alpha + bv;
          if (ACT == 1) v = fmaxf(v, 0.f);
          if (ACT == 2) v = 0.5f * v * (1.0f + erff(v * 0.7071067811865475f));
          const long off = Cz + (long)(grow0 + r) * ldc + cm;
          if (OUT == 0) ((float*)Cv)[off] = v;
          else ((ushort*)Cv)[off] = f2b(v);
        }
      }
    }
  }
}

// ---------------------------------------------------------------------------
// conv_down1 with A read DIRECTLY from x fp32 (fused transpose+bf16 cast).
// A[r][k] with r = b*2048+nn, k = t*128+d  ->  x[(b*12+t)*ND + nn*128 + d].
// Wave w's 2 A-frags live in registers (no LDS for A). Per (lr,lg) group the
// 4 lg-chunks cover 128B contiguous of each x row => full-line coalescing.
// bf16 values bit-identical to the old xt_k path. B staged as in mgemm.
// ---------------------------------------------------------------------------
__global__ __launch_bounds__(256) void mgemm_xa(
    const float* __restrict__ x, const ushort* __restrict__ B,
    const float* __restrict__ bias, ushort* __restrict__ C) {
  __shared__ ushort Bs[4096];
  const int tid = threadIdx.x;
  const int w = tid >> 6;
  const int l = tid & 63;
  const int lr = l & 15;
  const int lg = l >> 4;
  const int row0 = blockIdx.y * 128;
  const int b = row0 >> 11;
  const int nn0 = row0 & 2047;

  f32x4 acc[2][8];
#pragma unroll
  for (int i = 0; i < 2; ++i)
#pragma unroll
    for (int j = 0; j < 8; ++j) acc[i][j] = (f32x4){0.f, 0.f, 0.f, 0.f};

  const int ba = w, bb2 = w + 4;
  const ushort* Bpl = B + (long)(ba * 16 + lr) * 1536 + lg * 8;
  const ushort* Bpl2 = B + (long)(bb2 * 16 + lr) * 1536 + lg * 8;
  // per-wave A row offsets (within x, floats)
  const long ar0 = (long)(nn0 + w * 32 + 0 * 16 + lr) * 128;
  const long ar1 = (long)(nn0 + w * 32 + 1 * 16 + lr) * 128;

  for (int k0 = 0; k0 < 1536; k0 += 32) {
    const int t = k0 >> 7;
    const int df = (k0 & 127) + lg * 8;
    const float* xt_ = x + (((long)(b * 12 + t)) << 18) + df;
    f4u p0, p1, q0, q1;
    p0.v = *(const float4*)(xt_ + ar0);
    p1.v = *(const float4*)(xt_ + ar0 + 4);
    q0.v = *(const float4*)(xt_ + ar1);
    q1.v = *(const float4*)(xt_ + ar1 + 4);
    frag_u a0, a1;
#pragma unroll
    for (int j = 0; j < 4; ++j) {
      a0.u[j] = (unsigned)f2b(j < 2 ? p0.a[2 * j] : p1.a[2 * j - 4]) |
                ((unsigned)f2b(j < 2 ? p0.a[2 * j + 1] : p1.a[2 * j - 3]) << 16);
      a1.u[j] = (unsigned)f2b(j < 2 ? q0.a[2 * j] : q1.a[2 * j - 4]) |
                ((unsigned)f2b(j < 2 ? q0.a[2 * j + 1] : q1.a[2 * j - 3]) << 16);
    }
    gload16(Bpl + k0, Bs + ba * 512);
    gload16(Bpl2 + k0, Bs + bb2 * 512);
    __syncthreads();
#pragma unroll
    for (int ni = 0; ni < 8; ++ni) {
      const short8 bfr = *(const short8*)(Bs + ni * 512 + l * 8);
      acc[0][ni] = __builtin_amdgcn_mfma_f32_16x16x32_bf16(a0.s8, bfr, acc[0][ni], 0, 0, 0);
      acc[1][ni] = __builtin_amdgcn_mfma_f32_16x16x32_bf16(a1.s8, bfr, acc[1][ni], 0, 0, 0);
    }
    __syncthreads();
  }

#pragma unroll
  for (int mi = 0; mi < 2; ++mi) {
    const int grow0 = row0 + w * 32 + mi * 16 + lg * 4;
#pragma unroll
    for (int ni = 0; ni < 8; ++ni) {
      const int c = ni * 16 + lr;
      const float bv = bias[c];
#pragma unroll
      for (int r = 0; r < 4; ++r) {
        float v = fmaxf(acc[mi][ni][r] + bv, 0.f);
        C[(long)(grow0 + r) * 128 + c] = f2b(v);
      }
    }
  }
}

// ---------------------------------------------------------------------------
// conv_up GEMM2 fused with bias + residual(x fp32) + LayerNorm -> hn fp32.
// (unchanged)
// ---------------------------------------------------------------------------
__global__ __launch_bounds__(256) void mgemm_ln(
    const ushort* __restrict__ A, const ushort* __restrict__ B,
    const float* __restrict__ bias, const float* __restrict__ x,
    const float* __restrict__ gamma, const float* __restrict__ beta,
    float* __restrict__ hn) {
  const int K = 1536;
  __shared__ ushort As[4096];
  __shared__ ushort Bs[4096];
  const int tid = threadIdx.x;
  const int w = tid >> 6;
  const int l = tid & 63;
  const int lr = l & 15;
  const int lg = l >> 4;
  const int row0 = blockIdx.y * 128;
  const int t = blockIdx.x;
  const int col0 = t * 128;

  f32x4 acc[2][8];
#pragma unroll
  for (int i = 0; i < 2; ++i)
#pragma unroll
    for (int j = 0; j < 8; ++j) acc[i][j] = (f32x4){0.f, 0.f, 0.f, 0.f};

  const int ba = w, bb2 = w + 4;
  const ushort* Apl = A + (long)(row0 + ba * 16 + lr) * K + lg * 8;
  const ushort* Apl2 = A + (long)(row0 + bb2 * 16 + lr) * K + lg * 8;
  const ushort* Bpl = B + (long)(col0 + ba * 16 + lr) * K + lg * 8;
  const ushort* Bpl2 = B + (long)(col0 + bb2 * 16 + lr) * K + lg * 8;
  for (int k0 = 0; k0 < K; k0 += 32) {
    gload16(Apl + k0, As + ba * 512);
    gload16(Apl2 + k0, As + bb2 * 512);
    gload16(Bpl + k0, Bs + ba * 512);
    gload16(Bpl2 + k0, Bs + bb2 * 512);
    __syncthreads();
    const short8 a0 = *(const short8*)(As + (w * 2 + 0) * 512 + l * 8);
    const short8 a1 = *(const short8*)(As + (w * 2 + 1) * 512 + l * 8);
#pragma unroll
    for (int ni = 0; ni < 8; ++ni) {
      const short8 bfr = *(const short8*)(Bs + ni * 512 + l * 8);
      acc[0][ni] = __builtin_amdgcn_mfma_f32_16x16x32_bf16(a0, bfr, acc[0][ni], 0, 0, 0);
      acc[1][ni] = __builtin_amdgcn_mfma_f32_16x16x32_bf16(a1, bfr, acc[1][ni], 0, 0, 0);
    }
    __syncthreads();
  }

#pragma unroll
  for (int mi = 0; mi < 2; ++mi) {
#pragma unroll
    for (int r = 0; r < 4; ++r) {
      const int gr = row0 + w * 32 + mi * 16 + lg * 4 + r;
      const int bb = gr >> 11;
      const int nn = gr & 2047;
      const long base = ((long)(bb * 12 + t) << 18) + (long)nn * 128;
      float h[8];
      float s1 = 0.f, s2 = 0.f;
#pragma unroll
      for (int ni = 0; ni < 8; ++ni) {
        const int d = ni * 16 + lr;
        const float v = acc[mi][ni][r] + bias[col0 + d] + x[base + d];
        h[ni] = v;
        s1 += v;
        s2 += v * v;
      }
#pragma unroll
      for (int m = 1; m < 16; m <<= 1) {
        s1 += __shfl_xor(s1, m);
        s2 += __shfl_xor(s2, m);
      }
      const float mu = s1 * (1.f / 128.f);
      const float rstd = rsqrtf(s2 * (1.f / 128.f) - mu * mu + 1e-5f);
#pragma unroll
      for (int ni = 0; ni < 8; ++ni) {
        const int d = ni * 16 + lr;
        hn[base + d] = (h[ni] - mu) * rstd * gamma[d] + beta[d];
      }
    }
  }
}

// ---------------------------------------------------------------------------
// Flash attention: o = softmax(0.125 * q@k^T) @ v, per (128-q-tile, batch).
// grid (16, CB), 4 waves; wave owns 32 q-rows, iterates 16 key-tiles of 128.
// Q frags in regs (loaded once); K/V frags read DIRECTLY from global
// (qkb / vT slices are L2-resident, 1.5 MB per batch). Online softmax with
// mgemm_ln's 16-lane shfl reduce. P transposed via a per-wave LDS pane
// [32][136] (pad -> 2-way-conflict b128 reads). Waves fully independent:
// no __syncthreads anywhere.
// ---------------------------------------------------------------------------
__global__ __launch_bounds__(256) void attn_k(
    const ushort* __restrict__ qkb,   // [R][256] = [q|k]
    const ushort* __restrict__ vT,    // [128][R]
    ushort* __restrict__ o,           // [R][128]
    long R) {
  __shared__ __align__(16) ushort Pl[4][32][136];
  const int tid = threadIdx.x;
  const int w = tid >> 6;
  const int l = tid & 63;
  const int lr = l & 15;
  const int lg = l >> 4;
  const long zrow = (long)blockIdx.y * 2048;
  const int row0 = blockIdx.x * 128 + w * 32;   // q-row base of this wave

  // Q fragments (8 x short8 = 32 VGPR)
  frag_u qf[2][4];
#pragma unroll
  for (int f = 0; f < 2; ++f)
#pragma unroll
    for (int kc = 0; kc < 4; ++kc)
      qf[f][kc].u = *(const u32x4*)(qkb + (zrow + row0 + f * 16 + lr) * 256 + kc * 32 + lg * 8);

  f32x4 oa[2][8];
#pragma unroll
  for (int i = 0; i < 2; ++i)
#pragma unroll
    for (int j = 0; j < 8; ++j) oa[i][j] = (f32x4){0.f, 0.f, 0.f, 0.f};
  float mrow[2][4], lrow[2][4];
#pragma unroll
  for (int i = 0; i < 2; ++i)
#pragma unroll
    for (int r = 0; r < 4; ++r) { mrow[i][r] = -3.4e38f; lrow[i][r] = 0.f; }

#pragma unroll 1
  for (int kt = 0; kt < 16; ++kt) {
    const long kbase = zrow + kt * 128;
    // ---- S = q @ k^T (64 MFMA) ----
    f32x4 s[2][8];
#pragma unroll
    for (int i = 0; i < 2; ++i)
#pragma unroll
      for (int j = 0; j < 8; ++j) s[i][j] = (f32x4){0.f, 0.f, 0.f, 0.f};
#pragma unroll
    for (int kc = 0; kc < 4; ++kc) {
#pragma unroll
      for (int ni = 0; ni < 8; ++ni) {
        frag_u kf;
        kf.u = *(const u32x4*)(qkb + (kbase + ni * 16 + lr) * 256 + 128 + kc * 32 + lg * 8);
        s[0][ni] = __builtin_amdgcn_mfma_f32_16x16x32_bf16(qf[0][kc].s8, kf.s8, s[0][ni], 0, 0, 0);
        s[1][ni] = __builtin_amdgcn_mfma_f32_16x16x32_bf16(qf[1][kc].s8, kf.s8, s[1][ni], 0, 0, 0);
      }
    }
    // ---- online softmax (rows held by 16-lane lg-groups) ----
#pragma unroll
    for (int mi = 0; mi < 2; ++mi) {
#pragma unroll
      for (int r = 0; r < 4; ++r) {
        float mx = s[mi][0][r];
#pragma unroll
        for (int ni = 1; ni < 8; ++ni) mx = fmaxf(mx, s[mi][ni][r]);
#pragma unroll
        for (int msk = 1; msk < 16; msk <<= 1) mx = fmaxf(mx, __shfl_xor(mx, msk));
        mx *= 0.125f;
        const float mnew = fmaxf(mrow[mi][r], mx);
        const float psc = expf(mrow[mi][r] - mnew);
        mrow[mi][r] = mnew;
        float psum = 0.f;
#pragma unroll
        for (int ni = 0; ni < 8; ++ni) {
          const float p = expf(fmaf(s[mi][ni][r], 0.125f, -mnew));
          s[mi][ni][r] = p;
          psum += p;
        }
#pragma unroll
        for (int msk = 1; msk < 16; msk <<= 1) psum += __shfl_xor(psum, msk);
        lrow[mi][r] = lrow[mi][r] * psc + psum;
#pragma unroll
        for (int ni = 0; ni < 8; ++ni) oa[mi][ni][r] *= psc;
        const int q = mi * 16 + lg * 4 + r;
#pragma unroll
        for (int ni = 0; ni < 8; ++ni)
          Pl[w][q][ni * 16 + lr] = f2b(s[mi][ni][r]);
      }
    }
    // ---- o += P @ v (64 MFMA); P from LDS, V direct from vT ----
#pragma unroll
    for (int kc = 0; kc < 4; ++kc) {
      frag_u pa0, pa1;
      pa0.s8 = *(const short8*)(&Pl[w][lr][kc * 32 + lg * 8]);
      pa1.s8 = *(const short8*)(&Pl[w][16 + lr][kc * 32 + lg * 8]);
#pragma unroll
      for (int ni = 0; ni < 8; ++ni) {
        frag_u vf;
        vf.u = *(const u32x4*)(vT + (long)(ni * 16 + lr) * R + kbase + kc * 32 + lg * 8);
        oa[0][ni] = __builtin_amdgcn_mfma_f32_16x16x32_bf16(pa0.s8, vf.s8, oa[0][ni], 0, 0, 0);
        oa[1][ni] = __builtin_amdgcn_mfma_f32_16x16x32_bf16(pa1.s8, vf.s8, oa[1][ni], 0, 0, 0);
      }
    }
  }

  // epilogue: o[row][d] = oa / l
#pragma unroll
  for (int mi = 0; mi < 2; ++mi) {
#pragma unroll
    for (int r = 0; r < 4; ++r) {
      const float inv = 1.0f / lrow[mi][r];
      const long grow = zrow + row0 + mi * 16 + lg * 4 + r;
#pragma unroll
      for (int ni = 0; ni < 8; ++ni)
        o[grow * 128 + ni * 16 + lr] = f2b(oa[mi][ni][r] * inv);
    }
  }
}

// rfft over T=12: hn fp32 [CB,12,2048,128] -> re/im bf16 [CB,7,2048,128]
__global__ __launch_bounds__(256) void rfft_k(const float* __restrict__ hn,
                                              ushort* __restrict__ re,
                                              ushort* __restrict__ im) {
  const long i = (long)blockIdx.x * 256 + threadIdx.x;   // grid = CB*256
  const int bb = (int)(i >> 16);
  const int nd = (int)(i & 65535) * 4;
  f4u ht[12];
#pragma unroll
  for (int t = 0; t < 12; ++t)
    ht[t].v = *(const float4*)(hn + ((long)(bb * T_ + t) << 18) + nd);
#pragma unroll
  for (int f = 0; f < 7; ++f) {
    float sr[4] = {0.f, 0.f, 0.f, 0.f}, si[4] = {0.f, 0.f, 0.f, 0.f};
#pragma unroll
    for (int t = 0; t < 12; ++t) {
      const int k = (f * t) % 12;
      const float ck = COS12[k], sk = SIN12[k];
#pragma unroll
      for (int c = 0; c < 4; ++c) {
        sr[c] = fmaf(ht[t].a[c], ck, sr[c]);
        si[c] = fmaf(ht[t].a[c], sk, si[c]);
      }
    }
    const long off = ((long)(bb * 7 + f) << 18) + nd;
    ushort4 pr, pi;
    pr.x = f2b(sr[0]); pr.y = f2b(sr[1]); pr.z = f2b(sr[2]); pr.w = f2b(sr[3]);
    pi.x = f2b(-si[0]); pi.y = f2b(-si[1]); pi.z = f2b(-si[2]); pi.w = f2b(-si[3]);
    *(ushort4*)(re + off) = pr;
    *(ushort4*)(im + off) = pi;
  }
}

// irfft (n=12, numpy C2R) + residual -> fp32 out
__global__ __launch_bounds__(256) void irfft_k(const float* __restrict__ hr,
                                               const float* __restrict__ hi,
                                               const float* __restrict__ x,
                                               float* __restrict__ out) {
  const long i = (long)blockIdx.x * 256 + threadIdx.x;   // grid = CB*256
  const int bb = (int)(i >> 16);
  const int nd = (int)(i & 65535) * 4;
  f4u r[7], m[7];
#pragma unroll
  for (int f = 0; f < 7; ++f) {
    const long off = ((long)(bb * 7 + f) << 18) + nd;
    r[f].v = *(const float4*)(hr + off);
    m[f].v = *(const float4*)(hi + off);
  }
#pragma unroll
  for (int t = 0; t < 12; ++t) {
    const long xi = ((long)(bb * T_ + t) << 18) + nd;
    f4u xv;
    xv.v = *(const float4*)(x + xi);
    f4u s;
#pragma unroll
    for (int c = 0; c < 4; ++c)
      s.a[c] = r[0].a[c] + ((t & 1) ? -r[6].a[c] : r[6].a[c]);
#pragma unroll
    for (int f = 1; f < 6; ++f) {
      const int k = (f * t) % 12;
      const float ck = 2.0f * COS12[k], sk = 2.0f * SIN12[k];
#pragma unroll
      for (int c = 0; c < 4; ++c)
        s.a[c] += r[f].a[c] * ck - m[f].a[c] * sk;
    }
#pragma unroll
    for (int c = 0; c < 4; ++c) s.a[c] = s.a[c] * (1.0f / 12.0f) + xv.a[c];
    *(float4*)(out + xi) = s.v;
  }
}

// ---------------------------------------------------------------------------
// Weight prep (unchanged layout).
// ---------------------------------------------------------------------------
__global__ __launch_bounds__(256) void prep_k(
    const float* Wd1, const float* Wd2, const float* Wq, const float* Wk,
    const float* Wv, const float* Wu1, const float* Wu2, const float* Wr1,
    const float* Wr2, const float* Wi1, const float* Wi2,
    const float* bq, const float* bk, const float* br1, const float* bi1,
    const float* br2, const float* bi2,
    ushort* __restrict__ wws, float* __restrict__ bws) {
  const long i = (long)blockIdx.x * 256 + threadIdx.x;
  if (i < 256) bws[i] = (i < 128) ? bq[i] : bk[i - 128];
  else if (i < 512) { const int j = i - 256; bws[i] = (j < 128) ? br1[j] : bi1[j - 128]; }
  else if (i < 768) { const int j = i - 512; bws[i] = (j < 128) ? bi1[j] : br1[j - 128]; }
  else if (i < 896) { const int j = i - 768; bws[i] = br2[j] - bi2[j]; }
  else if (i < 1024) { const int j = i - 896; bws[i] = bi2[j] + br2[j]; }
  if (i >= 2949120) return;
  float v;
  if (i < 196608) v = Wd1[i];
  else if (i < 212992) v = Wd2[i - 196608];
  else if (i < 245760) { const long j = i - 212992; v = (j < 16384) ? Wq[j] : Wk[j - 16384]; }
  else if (i < 262144) v = Wv[i - 245760];
  else if (i < 458752) v = Wu1[i - 262144];
  else if (i < 2818048) v = Wu2[i - 458752];
  else if (i < 2850816) { const long j = i - 2818048; v = (j < 16384) ? Wr1[j] : Wi1[j - 16384]; }
  else if (i < 2883584) { const long j = i - 2850816; v = (j < 16384) ? Wi1[j] : Wr1[j - 16384]; }
  else if (i < 2916352) {
    const long j = i - 2883584; const int n = (int)(j >> 8), k = (int)(j & 255);
    v = (k < 128) ? Wr2[n * 128 + k] : -Wi2[n * 128 + k - 128];
  } else {
    const long j = i - 2916352; const int n = (int)(j >> 8), k = (int)(j & 255);
    v = (k < 128) ? Wi2[n * 128 + k] : Wr2[n * 128 + k - 128];
  }
  wws[i] = f2b(v);
}

// ---------------------------------------------------------------------------
extern "C" void kernel_launch(void* const* d_in, const int* in_sizes, int n_in,
                              void* d_out, int out_size, void* d_ws,
                              size_t ws_size, hipStream_t stream) {
  (void)in_sizes; (void)n_in; (void)out_size;
  const float* x   = (const float*)d_in[0];
  const float* Wd1 = (const float*)d_in[1];
  const float* bd1 = (const float*)d_in[2];
  const float* Wd2 = (const float*)d_in[3];
  const float* bd2 = (const float*)d_in[4];
  const float* Wq  = (const float*)d_in[5];
  const float* bq  = (const float*)d_in[6];
  const float* Wk  = (const float*)d_in[7];
  const float* bk  = (const float*)d_in[8];
  const float* Wv  = (const float*)d_in[9];
  const float* bv  = (const float*)d_in[10];
  const float* Wu1 = (const float*)d_in[11];
  const float* bu1 = (const float*)d_in[12];
  const float* Wu2 = (const float*)d_in[13];
  const float* bu2 = (const float*)d_in[14];
  const float* gamma = (const float*)d_in[15];
  const float* beta  = (const float*)d_in[16];
  const float* Wr1 = (const float*)d_in[17];
  const float* br1 = (const float*)d_in[18];
  const float* Wr2 = (const float*)d_in[19];
  const float* br2 = (const float*)d_in[20];
  const float* Wi1 = (const float*)d_in[21];
  const float* bi1 = (const float*)d_in[22];
  const float* Wi2 = (const float*)d_in[23];
  const float* bi2 = (const float*)d_in[24];
  float* out = (float*)d_out;

  // ---- workspace carve-up (unchanged; xt/P/S now unused but reserved) ----
  float* bws = (float*)d_ws;                   // 1024 f32
  ushort* wws = (ushort*)(bws + 1024);         // 2949120 ushort
  const size_t kFixed = 1024 * 4 + 2949120 * 2;   // 5902336 B
  const size_t kPerBatch = 90177536;              // bytes
  int CB = 1;
  const int cands[5] = {16, 8, 4, 2, 1};
  for (int ci = 0; ci < 5; ++ci)
    if (kFixed + (size_t)cands[ci] * kPerBatch <= ws_size) { CB = cands[ci]; break; }

  char* base = (char*)d_ws + kFixed;
  const long R = (long)CB * N_;            // conv rows per chunk
  const long Fr = (long)CB * 7 * N_;       // fft rows per chunk
  ushort* xt  = (ushort*)base;             // CB*3145728 (unused)
  ushort* y1  = xt  + CB * 3145728L;       // R*128
  ushort* y   = y1  + R * 128;             // R*128
  ushort* qkb = y   + R * 128;             // R*256
  ushort* vT  = qkb + R * 256;             // 128*R
  ushort* P   = vT  + R * 128;             // CB*2048*2048 (unused)
  ushort* o   = P   + (long)CB * N_ * N_;  // R*128
  ushort* u1  = o   + R * 128;             // R*1536
  ushort* re  = u1  + R * 1536;            // Fr*128
  ushort* im  = re  + Fr * 128;            // Fr*128
  ushort* G   = im  + Fr * 128;            // Fr*512
  float*  S   = (float*)(G + Fr * 512);    // CB*2048*2048 (unused)
  float*  hn  = S   + (long)CB * N_ * N_;  // R*1536
  float*  hr  = hn  + R * 1536;            // Fr*128
  float*  hi  = hr  + Fr * 128;            // Fr*128

  const dim3 blk(256);

  // weight prep (once per call; ~6 MB)
  prep_k<<<dim3(11520), blk, 0, stream>>>(Wd1, Wd2, Wq, Wk, Wv, Wu1, Wu2,
                                          Wr1, Wr2, Wi1, Wi2, bq, bk, br1,
                                          bi1, br2, bi2, wws, bws);
  ushort* Wd1b = wws;
  ushort* Wd2b = wws + 196608;
  ushort* Wqkb = wws + 212992;
  ushort* Wvb  = wws + 245760;
  ushort* Wu1b = wws + 262144;
  ushort* Wu2b = wws + 458752;
  ushort* W13b = wws + 2818048;
  ushort* W24b = wws + 2850816;
  ushort* Whrb = wws + 2883584;
  ushort* Whib = wws + 2916352;
  float* bqk = bws;
  float* b13 = bws + 256;
  float* b24 = bws + 512;
  float* bhr = bws + 768;
  float* bhi = bws + 896;

  for (int c = 0; c < 16 / CB; ++c) {
    const int b0 = c * CB;
    const float* xc = x + (long)b0 * TND_;
    float* oc = out + (long)b0 * TND_;
    const int GY = CB * 16;     // R/128
    const int GF = CB * 112;    // Fr/128

    // conv_down1 (A direct from x): y1 = relu(xt@Wd1^T+bd1)
    mgemm_xa<<<dim3(1, GY), blk, 0, stream>>>(xc, Wd1b, bd1, y1);
    // conv_down2: y = y1@Wd2^T+bd2
    mgemm<0, 1><<<dim3(1, GY), blk, 0, stream>>>(
        y1, Wd2b, bd2, y, 128, 128, 128, 128, 1.f, 0, 0, 0, 0, 0);
    // [q|k] and v^T
    mgemm<0, 1><<<dim3(2, GY), blk, 0, stream>>>(
        y, Wqkb, bqk, qkb, 128, 128, 128, 256, 1.f, 0, 0, 0, 0, 0);
    mgemm<0, 2><<<dim3(1, GY), blk, 0, stream>>>(
        y, Wvb, bv, vT, 128, 128, 128, (int)R, 1.f, 0, 0, 0, 0, 0);
    // flash attention: o = softmax(0.125 q k^T) v
    attn_k<<<dim3(16, CB), blk, 0, stream>>>(qkb, vT, o, R);
    // conv_up: u1 = relu(o@Wu1^T+bu1); GEMM2+residual+LN -> hn
    mgemm<1, 1><<<dim3(12, GY), blk, 0, stream>>>(
        o, Wu1b, bu1, u1, 128, 128, 128, 1536, 1.f, 0, 0, 0, 0, 0);
    mgemm_ln<<<dim3(12, GY), blk, 0, stream>>>(u1, Wu2b, bu2, xc, gamma, beta, hn);
    // rfft
    rfft_k<<<dim3(CB * 256), blk, 0, stream>>>(hn, re, im);
    // FFT MLP layer 1 (concat): re -> [g1|g3], im -> [g2|g4] in G[M][512]
    mgemm<2, 1><<<dim3(2, GF), blk, 0, stream>>>(
        re, W13b, b13, G, 128, 128, 128, 512, 1.f, 0, 0, 0, 0, 128);
    mgemm<2, 1><<<dim3(2, GF), blk, 0, stream>>>(
        im, W24b, b24, G, 128, 128, 128, 512, 1.f, 0, 0, 0, 128, 256);
    // FFT MLP layer 2 (K=256 concat, sign-folded): hr, hi fp32
    mgemm<0, 0><<<dim3(1, GF), blk, 0, stream>>>(
        G, Whrb, bhr, hr, 256, 512, 256, 128, 1.f, 0, 0, 0, 0, 0);
    mgemm<0, 0><<<dim3(1, GF), blk, 0, stream>>>(
        G + 256, Whib, bhi, hi, 256, 512, 256, 128, 1.f, 0, 0, 0, 0, 0);
    // irfft + residual
    irfft_k<<<dim3(CB * 256), blk, 0, stream>>>(hr, hi, xc, oc);
  }
}